// Round 7
// baseline (313.928 us; speedup 1.0000x reference)
//
#include <hip/hip_runtime.h>
#include <hip/hip_bf16.h>

#define NQ_   8192
#define DM_   256
#define NH_   6
#define DH_   64
#define BATCH 2

typedef __attribute__((ext_vector_type(8))) short short8;
typedef __attribute__((ext_vector_type(4))) short short4v;
typedef __attribute__((ext_vector_type(4))) float float4v;

// ---------------- workspace layout ----------------
static const size_t VOFF_L0 = 0;
static const size_t VOFF_L1 = 5898240;
static const size_t VOFF_L2 = 7372800;
static const size_t QRAW_BYTE_OFF  = 15482880;
static const size_t MID_BYTE_OFF   = 47333376;   // mid bf16 [16384][384]
static const size_t QBF_BYTE_OFF   = 47333376;   // qbf bf16 [16384][256] — aliases mid (lifetimes disjoint)
static const size_t WT_BYTE_OFF    = 59916288;
static const size_t FEATT_BYTE_OFF = 60558336;
// wT element offsets
static const size_t WVT_OFF   = 0;        // 384 rows x 256
static const size_t WOFFT_OFF = 98304;    // 324 rows x 256
static const size_t WOUTT_OFF = 222720;   // 256 rows x 384
// featT element offsets
static const size_t FT_L0 = 0;
static const size_t FT_L1 = 3932160;
static const size_t FT_L2 = 4915200;

__device__ __forceinline__ unsigned short f2bf(float f) {
    unsigned int u = __float_as_uint(f);
    unsigned int r = (u + 0x7fffu + ((u >> 16) & 1u)) >> 16;
    return (unsigned short)r;
}

// ============ prep_all: weights T (0..1125) | feat T (1126..6165) | qbf = bf16(x+pe) (6166..7189) ============
__global__ __launch_bounds__(256) void prep_all(const float* __restrict__ Wv,
                                                const float* __restrict__ Woff,
                                                const float* __restrict__ Wattn,
                                                const float* __restrict__ Wout,
                                                const float* __restrict__ feat0,
                                                const float* __restrict__ feat1,
                                                const float* __restrict__ feat2,
                                                const float* __restrict__ x,
                                                const float* __restrict__ pe,
                                                unsigned short* __restrict__ wT,
                                                unsigned short* __restrict__ fT,
                                                unsigned short* __restrict__ qbf) {
    const int pid = blockIdx.x, t = threadIdx.x;
    if (pid < 1126) {
        int r = pid;
        const float* src; int N, n, K; size_t doff;
        if (r < 384)      { src = Wv;    N = 384; n = r;       K = 256; doff = (size_t)r * 256; }
        else if (r < 708) { src = Woff;  N = 324; n = r - 384; K = 256; doff = (size_t)r * 256; }
        else if (r < 870) { src = Wattn; N = 162; n = r - 708; K = 256; doff = (size_t)r * 256; }
        else              { src = Wout;  N = 256; n = r - 870; K = 384; doff = WOUTT_OFF + (size_t)(r - 870) * 384; }
        for (int k = t; k < K; k += 256) wT[doff + k] = f2bf(src[(size_t)k * N + n]);
        return;
    }
    if (pid < 6166) {
        __shared__ float tile[32][33];
        int f = pid - 1126;
        const float* src; unsigned short* dst; int HW;
        if (f < 3840)      { src = feat0; dst = fT + FT_L0; HW = 7680; }
        else if (f < 4800) { src = feat1; dst = fT + FT_L1; HW = 1920; f -= 3840; }
        else               { src = feat2; dst = fT + FT_L2; HW = 480;  f -= 4800; }
        int pb = f >> 4, rem = f & 15, cb = rem >> 1, b = rem & 1;
        int p0 = pb * 32, c0 = cb * 32;
        int tx = t & 31, ty = t >> 5;
#pragma unroll
        for (int i = 0; i < 4; ++i) {
            int c = c0 + ty + i * 8;
            tile[ty + i * 8][tx] = src[((size_t)(b * DM_ + c)) * HW + p0 + tx];
        }
        __syncthreads();
#pragma unroll
        for (int i = 0; i < 4; ++i) {
            int p = p0 + ty + i * 8;
            dst[((size_t)b * HW + p) * DM_ + c0 + tx] = f2bf(tile[tx][ty + i * 8]);
        }
        return;
    }
    // qbf: 1024 blocks, 4096 elements each
    int f = pid - 6166;
#pragma unroll
    for (int i = 0; i < 4; ++i) {
        size_t e = (size_t)f * 4096 + i * 1024 + t * 4;
        float4 xv = *(const float4*)&x[e];
        float4 pv = *(const float4*)&pe[e];
        short4v o;
        o[0] = (short)f2bf(xv.x + pv.x);
        o[1] = (short)f2bf(xv.y + pv.y);
        o[2] = (short)f2bf(xv.z + pv.z);
        o[3] = (short)f2bf(xv.w + pv.w);
        *(short4v*)&qbf[e] = o;
    }
}

// ============ shared MFMA inner block: 128x128 tile, 4 waves 2x2, 4x4 frags ============
__device__ __forceinline__ void mfma_block(const short A[][40], const short B[][40],
                                           int wm, int wn, int lane, float4v acc[4][4]) {
    int m_base = wm + (lane & 15);
    int n_base = wn + (lane & 15);
    int q8 = (lane >> 4) * 8;
    short8 af[4], bf[4];
#pragma unroll
    for (int i = 0; i < 4; ++i) af[i] = *(const short8*)&A[m_base + i * 16][q8];
#pragma unroll
    for (int j = 0; j < 4; ++j) bf[j] = *(const short8*)&B[n_base + j * 16][q8];
#pragma unroll
    for (int i = 0; i < 4; ++i)
#pragma unroll
        for (int j = 0; j < 4; ++j)
            acc[i][j] = __builtin_amdgcn_mfma_f32_16x16x32_bf16(af[i], bf[j], acc[i][j], 0, 0, 0);
}

// ============ fused value GEMM (blocks 0..473) + query GEMM (blocks 474..985) ============
__global__ __launch_bounds__(256) void gemm_vq(const unsigned short* __restrict__ fT,
                                               const unsigned short* __restrict__ wT,
                                               const float* __restrict__ bv,
                                               unsigned short* __restrict__ vws,
                                               const unsigned short* __restrict__ qbf,
                                               const float* __restrict__ boff,
                                               const float* __restrict__ battn,
                                               float* __restrict__ qraw) {
    __shared__ short A[128][40];
    __shared__ short B[128][40];
    const int tid = threadIdx.x;
    const int lane = tid & 63, wave = tid >> 6;
    const int wm = (wave & 1) * 64, wn = (wave >> 1) * 64;
    const int id = blockIdx.x;
    float4v acc[4][4];
#pragma unroll
    for (int i = 0; i < 4; ++i)
#pragma unroll
        for (int j = 0; j < 4; ++j) acc[i][j] = (float4v){0.f, 0.f, 0.f, 0.f};

    if (id < 474) {
        // ---- value path ----
        int pb = id / 6, rem = id % 6;
        int nb = rem >> 1, b = rem & 1;
        int pbl, HW; size_t ftoff, voff;
        if (pb < 60)      { pbl = pb;      HW = 7680; ftoff = FT_L0; voff = VOFF_L0; }
        else if (pb < 75) { pbl = pb - 60; HW = 1920; ftoff = FT_L1; voff = VOFF_L1; }
        else              { pbl = pb - 75; HW = 480;  ftoff = FT_L2; voff = VOFF_L2; }
        const int p0 = pbl * 128, n0 = nb * 128;
        const unsigned short* Asrc = fT + ftoff + (size_t)b * HW * DM_;
        const unsigned short* wvT = wT + WVT_OFF;

        for (int k0 = 0; k0 < DM_; k0 += 32) {
#pragma unroll
            for (int it = 0; it < 2; ++it) {
                int idx = tid + it * 256;
                int r = idx >> 2, sg = idx & 3;
                int p = p0 + r; if (p >= HW) p = HW - 1;
                *(short8*)&A[r][sg * 8] = *(const short8*)&Asrc[(size_t)p * DM_ + k0 + sg * 8];
                *(short8*)&B[r][sg * 8] = *(const short8*)&wvT[(size_t)(n0 + r) * DM_ + k0 + sg * 8];
            }
            __syncthreads();
            mfma_block(A, B, wm, wn, lane, acc);
            __syncthreads();
        }
        int colb = n0 + wn + (lane & 15);
        int rowq = (lane >> 4) * 4;
#pragma unroll
        for (int i = 0; i < 4; ++i)
#pragma unroll
            for (int j = 0; j < 4; ++j) {
                int n = colb + j * 16;
                int h = n >> 6, d = n & 63;
                float bias = bv[n];
#pragma unroll
                for (int r = 0; r < 4; ++r) {
                    int p = p0 + wm + i * 16 + rowq + r;
                    if (p < HW)
                        vws[voff + ((size_t)(b * NH_ + h) * HW + p) * DH_ + d] = f2bf(acc[i][j][r] + bias);
                }
            }
    } else {
        // ---- query path (bf16 staging from qbf) ----
        int qid = id - 474;
        const int m0 = (qid & 127) * 128, n0 = (qid >> 7) * 128;
        for (int k0 = 0; k0 < DM_; k0 += 32) {
#pragma unroll
            for (int it = 0; it < 2; ++it) {
                int idx = tid + it * 256;
                int r = idx >> 2, sg = idx & 3;
                *(short8*)&A[r][sg * 8] = *(const short8*)&qbf[(size_t)(m0 + r) * DM_ + k0 + sg * 8];
                int g = n0 + r;
                short8 bz = (short8)0;
                if (g < 486) bz = *(const short8*)&wT[WOFFT_OFF + (size_t)g * DM_ + k0 + sg * 8];
                *(short8*)&B[r][sg * 8] = bz;
            }
            __syncthreads();
            mfma_block(A, B, wm, wn, lane, acc);
            __syncthreads();
        }
        int colb = n0 + wn + (lane & 15);
        int rowq = (lane >> 4) * 4;
#pragma unroll
        for (int i = 0; i < 4; ++i)
#pragma unroll
            for (int j = 0; j < 4; ++j) {
                int n = colb + j * 16;
                if (n < 486) {
                    float bias = (n < 324) ? boff[n] : battn[n - 324];
#pragma unroll
                    for (int r = 0; r < 4; ++r) {
                        int m = m0 + wm + i * 16 + rowq + r;
                        qraw[(size_t)m * 486 + n] = acc[i][j][r] + bias;
                    }
                }
            }
    }
}

// ============ fused softmax + projection + gather, 2 queries per block ============
// plan LDS (flat): plane = q*4 + corner (corner = (y<<1)|x); entry = plane*177 + h*27 + tap
//   entry = {abs byte off (level+slice+y+x baked), weight bits}
// gather lanes: q = lane>>5, corner = (lane>>3)&3, chunk = lane&7 (16B of the 128B pixel row)
// one global_load_dwordx4 per tap covers BOTH queries and all 4 corners.
__global__ __launch_bounds__(384, 6) void sample_kernel(const float* __restrict__ qraw,
                                                        const float* __restrict__ coor,
                                                        const float* __restrict__ cam2img,
                                                        const float* __restrict__ l2c,
                                                        const unsigned short* __restrict__ vws,
                                                        unsigned short* __restrict__ mid) {
    __shared__ int2 s_plan[1416];   // 8 planes x 177 (pad: 177*8B = 354 dwords ≡ 2 mod 32 -> conflict-free)
    const int tid = threadIdx.x;
    const int bq0 = blockIdx.x * 2;

    {
        int q = tid >= 192;
        int t = tid - q * 192;
        int bq = bq0 + q;
        int b = bq >> 13;
        int h = t >> 5, j = t & 31;
        bool act = j < 27;
        float logit = act ? qraw[(size_t)bq * 486 + 324 + h * 27 + j] : -1e30f;
        float m = logit;
#pragma unroll
        for (int msk = 16; msk >= 1; msk >>= 1) m = fmaxf(m, __shfl_xor(m, msk, 32));
        float e = act ? __expf(logit - m) : 0.f;
        float ssum = e;
#pragma unroll
        for (int msk = 16; msk >= 1; msk >>= 1) ssum += __shfl_xor(ssum, msk, 32);
        if (act) {
            float attn = e * __frcp_rn(ssum);
            int l = (j >= 18) ? 2 : ((j >= 9) ? 1 : 0);
            int wl = 160 >> l, hl = 48 >> l;
            int HWl = (l == 0) ? 7680 : ((l == 1) ? 1920 : 480);
            int lvlb = (l == 0) ? 0 : ((l == 1) ? 11796480 : 14745600);
            float sc = (l == 0) ? 0.125f : ((l == 1) ? 0.0625f : 0.03125f);
            float c0 = coor[(size_t)bq * 3 + 0];
            float c1 = coor[(size_t)bq * 3 + 1];
            float c2 = coor[(size_t)bq * 3 + 2];
            const float* L = l2c + b * 16;
            const float* C = cam2img + b * 16;
            float pc0 = L[0] * c0 + L[1] * c1 + L[2]  * c2 + L[3];
            float pc1 = L[4] * c0 + L[5] * c1 + L[6]  * c2 + L[7];
            float pc2 = L[8] * c0 + L[9] * c1 + L[10] * c2 + L[11];
            float q0 = C[0] * pc0 + C[1] * pc1 + C[2]  * pc2 + C[3];
            float q1 = C[4] * pc0 + C[5] * pc1 + C[6]  * pc2 + C[7];
            float q2 = C[8] * pc0 + C[9] * pc1 + C[10] * pc2 + C[11];
            float rz = __frcp_rn(q2);
            float refx = q0 * rz * sc, refy = q1 * rz * sc;
            float2 oxy = *(const float2*)&qraw[(size_t)bq * 486 + h * 54 + j * 2];
            float X = refx + oxy.x - 0.5f;
            float Y = refy + oxy.y - 0.5f;
            float x0f = floorf(X), y0f = floorf(Y);
            float fx = X - x0f, fy = Y - y0f;
            int ix = (int)x0f, iy = (int)y0f;
            int bx = min(max(ix, 0), wl - 2);
            float wx0 = ((bx == ix) ? (1.f - fx) : 0.f) + ((bx == ix + 1) ? fx : 0.f);
            float wx1 = ((bx + 1 == ix) ? (1.f - fx) : 0.f) + ((bx + 1 == ix + 1) ? fx : 0.f);
            int cy0 = min(max(iy, 0), hl - 1);
            int cy1 = min(max(iy + 1, 0), hl - 1);
            float wy0 = (iy >= 0 && iy < hl) ? (1.f - fy) : 0.f;
            float wy1 = (iy + 1 >= 0 && iy + 1 < hl) ? fy : 0.f;
            int jj = h * 27 + j;
            int slice = (b * NH_ + h) * HWl;
            int off0 = lvlb + (slice + cy0 * wl + bx) * 128;
            int off1 = lvlb + (slice + cy1 * wl + bx) * 128;
            int pb = q * 4 * 177 + jj;
            s_plan[pb]           = make_int2(off0,       __float_as_int(attn * wy0 * wx0));
            s_plan[pb + 177]     = make_int2(off0 + 128, __float_as_int(attn * wy0 * wx1));
            s_plan[pb + 2 * 177] = make_int2(off1,       __float_as_int(attn * wy1 * wx0));
            s_plan[pb + 3 * 177] = make_int2(off1 + 128, __float_as_int(attn * wy1 * wx1));
        }
    }
    __syncthreads();

    const int h = tid >> 6;
    const int lane = tid & 63;
    const int plane = lane >> 3;                     // q*4 + corner
    const unsigned cb = (unsigned)((lane & 7) << 4); // 16B chunk within pixel row
    const char* vbase = (const char*)vws;
    const int2* pl = &s_plan[plane * 177 + h * 27];
    float a[8];
#pragma unroll
    for (int i = 0; i < 8; ++i) a[i] = 0.f;

    int g0 = 0;
#pragma unroll
    for (int g = 0; g < 4; ++g) {
        const int N = (g < 3) ? 7 : 6;
        int2 pw[7];
        uint4 d[7];
#pragma unroll
        for (int t = 0; t < N; ++t) pw[t] = pl[g0 + t];
#pragma unroll
        for (int t = 0; t < N; ++t) d[t] = *(const uint4*)(vbase + ((unsigned)pw[t].x + cb));
#pragma unroll
        for (int t = 0; t < N; ++t) {
            float w = __int_as_float(pw[t].y);
            a[0] = fmaf(w, __uint_as_float(d[t].x << 16), a[0]);
            a[1] = fmaf(w, __uint_as_float(d[t].x & 0xffff0000u), a[1]);
            a[2] = fmaf(w, __uint_as_float(d[t].y << 16), a[2]);
            a[3] = fmaf(w, __uint_as_float(d[t].y & 0xffff0000u), a[3]);
            a[4] = fmaf(w, __uint_as_float(d[t].z << 16), a[4]);
            a[5] = fmaf(w, __uint_as_float(d[t].z & 0xffff0000u), a[5]);
            a[6] = fmaf(w, __uint_as_float(d[t].w << 16), a[6]);
            a[7] = fmaf(w, __uint_as_float(d[t].w & 0xffff0000u), a[7]);
        }
        g0 += N;
    }

    // reduce over corner bits (lane bits 3,4)
#pragma unroll
    for (int i = 0; i < 8; ++i) {
        a[i] += __shfl_xor(a[i], 8, 64);
        a[i] += __shfl_xor(a[i], 16, 64);
    }
    if (((lane >> 3) & 3) == 0) {
        int q = lane >> 5;
        uint4 pk;
        pk.x = (unsigned)f2bf(a[0]) | ((unsigned)f2bf(a[1]) << 16);
        pk.y = (unsigned)f2bf(a[2]) | ((unsigned)f2bf(a[3]) << 16);
        pk.z = (unsigned)f2bf(a[4]) | ((unsigned)f2bf(a[5]) << 16);
        pk.w = (unsigned)f2bf(a[6]) | ((unsigned)f2bf(a[7]) << 16);
        *(uint4*)&mid[(size_t)(bq0 + q) * 384 + h * DH_ + ((lane & 7) << 3)] = pk;
    }
}

// ============ out GEMM: 64x128 tiles (512 blocks, 2/CU) ============
__global__ __launch_bounds__(256) void out_gemm(const unsigned short* __restrict__ mid,
                                                const unsigned short* __restrict__ woT,
                                                const float* __restrict__ bout,
                                                float* __restrict__ out) {
    __shared__ short A[64][40];
    __shared__ short B[128][40];
    const int tid = threadIdx.x;
    const int m0 = blockIdx.x * 64, n0 = blockIdx.y * 128;
    const int lane = tid & 63, wave = tid >> 6;
    const int wn = wave * 32;
    float4v acc[4][2];
#pragma unroll
    for (int i = 0; i < 4; ++i)
#pragma unroll
        for (int j = 0; j < 2; ++j) acc[i][j] = (float4v){0.f, 0.f, 0.f, 0.f};

    for (int k0 = 0; k0 < 384; k0 += 32) {
        {
            int r = tid >> 2, sg = tid & 3;
            *(short8*)&A[r][sg * 8] = *(const short8*)&mid[(size_t)(m0 + r) * 384 + k0 + sg * 8];
        }
#pragma unroll
        for (int it = 0; it < 2; ++it) {
            int idx = tid + it * 256;
            int r = idx >> 2, sg = idx & 3;
            *(short8*)&B[r][sg * 8] = *(const short8*)&woT[(size_t)(n0 + r) * 384 + k0 + sg * 8];
        }
        __syncthreads();
        {
            int m_base = lane & 15;
            int n_base = wn + (lane & 15);
            int q8 = (lane >> 4) * 8;
            short8 af[4], bf[2];
#pragma unroll
            for (int i = 0; i < 4; ++i) af[i] = *(const short8*)&A[m_base + i * 16][q8];
#pragma unroll
            for (int j = 0; j < 2; ++j) bf[j] = *(const short8*)&B[n_base + j * 16][q8];
#pragma unroll
            for (int i = 0; i < 4; ++i)
#pragma unroll
                for (int j = 0; j < 2; ++j)
                    acc[i][j] = __builtin_amdgcn_mfma_f32_16x16x32_bf16(af[i], bf[j], acc[i][j], 0, 0, 0);
        }
        __syncthreads();
    }
    int colb = n0 + wn + (lane & 15);
    int rowq = (lane >> 4) * 4;
#pragma unroll
    for (int i = 0; i < 4; ++i)
#pragma unroll
        for (int j = 0; j < 2; ++j) {
            int n = colb + j * 16;
            float bias = bout[n];
#pragma unroll
            for (int r = 0; r < 4; ++r) {
                int m = m0 + i * 16 + rowq + r;
                out[(size_t)m * 256 + n] = acc[i][j][r] + bias;
            }
        }
}

extern "C" void kernel_launch(void* const* d_in, const int* in_sizes, int n_in,
                              void* d_out, int out_size, void* d_ws, size_t ws_size,
                              hipStream_t stream) {
    const float* x      = (const float*)d_in[0];
    const float* pe     = (const float*)d_in[1];
    const float* coor   = (const float*)d_in[2];
    const float* c2i    = (const float*)d_in[3];
    const float* l2c    = (const float*)d_in[4];
    const float* feat0  = (const float*)d_in[5];
    const float* feat1  = (const float*)d_in[6];
    const float* feat2  = (const float*)d_in[7];
    const float* Wv     = (const float*)d_in[8];
    const float* bv     = (const float*)d_in[9];
    const float* Woff   = (const float*)d_in[10];
    const float* boff   = (const float*)d_in[11];
    const float* Wattn  = (const float*)d_in[12];
    const float* battn  = (const float*)d_in[13];
    const float* Wout   = (const float*)d_in[14];
    const float* bout   = (const float*)d_in[15];

    unsigned short* vws = (unsigned short*)d_ws;
    float* qraw         = (float*)((char*)d_ws + QRAW_BYTE_OFF);
    unsigned short* mid = (unsigned short*)((char*)d_ws + MID_BYTE_OFF);
    unsigned short* qbf = (unsigned short*)((char*)d_ws + QBF_BYTE_OFF);
    unsigned short* wT  = (unsigned short*)((char*)d_ws + WT_BYTE_OFF);
    unsigned short* fT  = (unsigned short*)((char*)d_ws + FEATT_BYTE_OFF);
    float* out          = (float*)d_out;

    prep_all<<<dim3(7190), 256, 0, stream>>>(Wv, Woff, Wattn, Wout, feat0, feat1, feat2,
                                             x, pe, wT, fT, qbf);
    gemm_vq<<<dim3(986), 256, 0, stream>>>(fT, wT, bv, vws, qbf, boff, battn, qraw);
    sample_kernel<<<dim3(BATCH * NQ_ / 2), 384, 0, stream>>>(qraw, coor, c2i, l2c, vws, mid);
    out_gemm<<<dim3(256, 2), 256, 0, stream>>>(mid, wT + WOUTT_OFF, bout, out);
}

// Round 8
// 229.248 us; speedup vs baseline: 1.3694x; 1.3694x over previous
//
#include <hip/hip_runtime.h>
#include <hip/hip_bf16.h>

#define NQ_   8192
#define DM_   256
#define NH_   6
#define DH_   64
#define BATCH 2

typedef __attribute__((ext_vector_type(8))) short short8;
typedef __attribute__((ext_vector_type(4))) short short4v;
typedef __attribute__((ext_vector_type(4))) float float4v;

// ---------------- workspace layout ----------------
static const size_t VOFF_L0 = 0;
static const size_t VOFF_L1 = 5898240;
static const size_t VOFF_L2 = 7372800;
static const size_t QRAW_BYTE_OFF  = 15482880;
static const size_t MID_BYTE_OFF   = 47333376;   // mid bf16 [16384][384]
static const size_t QBF_BYTE_OFF   = 47333376;   // qbf bf16 [16384][256] — aliases mid (lifetimes disjoint)
static const size_t WT_BYTE_OFF    = 59916288;
static const size_t FEATT_BYTE_OFF = 60558336;
// wT element offsets
static const size_t WVT_OFF   = 0;        // 384 rows x 256
static const size_t WOFFT_OFF = 98304;    // 324 rows x 256
static const size_t WOUTT_OFF = 222720;   // 256 rows x 384
// featT element offsets
static const size_t FT_L0 = 0;
static const size_t FT_L1 = 3932160;
static const size_t FT_L2 = 4915200;

__device__ __forceinline__ unsigned short f2bf(float f) {
    unsigned int u = __float_as_uint(f);
    unsigned int r = (u + 0x7fffu + ((u >> 16) & 1u)) >> 16;
    return (unsigned short)r;
}

// ============ prep_all: weights T (0..1125) | feat T (1126..6165) | qbf = bf16(x+pe) (6166..7189) ============
__global__ __launch_bounds__(256) void prep_all(const float* __restrict__ Wv,
                                                const float* __restrict__ Woff,
                                                const float* __restrict__ Wattn,
                                                const float* __restrict__ Wout,
                                                const float* __restrict__ feat0,
                                                const float* __restrict__ feat1,
                                                const float* __restrict__ feat2,
                                                const float* __restrict__ x,
                                                const float* __restrict__ pe,
                                                unsigned short* __restrict__ wT,
                                                unsigned short* __restrict__ fT,
                                                unsigned short* __restrict__ qbf) {
    const int pid = blockIdx.x, t = threadIdx.x;
    if (pid < 1126) {
        int r = pid;
        const float* src; int N, n, K; size_t doff;
        if (r < 384)      { src = Wv;    N = 384; n = r;       K = 256; doff = (size_t)r * 256; }
        else if (r < 708) { src = Woff;  N = 324; n = r - 384; K = 256; doff = (size_t)r * 256; }
        else if (r < 870) { src = Wattn; N = 162; n = r - 708; K = 256; doff = (size_t)r * 256; }
        else              { src = Wout;  N = 256; n = r - 870; K = 384; doff = WOUTT_OFF + (size_t)(r - 870) * 384; }
        for (int k = t; k < K; k += 256) wT[doff + k] = f2bf(src[(size_t)k * N + n]);
        return;
    }
    if (pid < 6166) {
        __shared__ float tile[32][33];
        int f = pid - 1126;
        const float* src; unsigned short* dst; int HW;
        if (f < 3840)      { src = feat0; dst = fT + FT_L0; HW = 7680; }
        else if (f < 4800) { src = feat1; dst = fT + FT_L1; HW = 1920; f -= 3840; }
        else               { src = feat2; dst = fT + FT_L2; HW = 480;  f -= 4800; }
        int pb = f >> 4, rem = f & 15, cb = rem >> 1, b = rem & 1;
        int p0 = pb * 32, c0 = cb * 32;
        int tx = t & 31, ty = t >> 5;
#pragma unroll
        for (int i = 0; i < 4; ++i) {
            int c = c0 + ty + i * 8;
            tile[ty + i * 8][tx] = src[((size_t)(b * DM_ + c)) * HW + p0 + tx];
        }
        __syncthreads();
#pragma unroll
        for (int i = 0; i < 4; ++i) {
            int p = p0 + ty + i * 8;
            dst[((size_t)b * HW + p) * DM_ + c0 + tx] = f2bf(tile[tx][ty + i * 8]);
        }
        return;
    }
    // qbf: 1024 blocks, 4096 elements each
    int f = pid - 6166;
#pragma unroll
    for (int i = 0; i < 4; ++i) {
        size_t e = (size_t)f * 4096 + i * 1024 + t * 4;
        float4 xv = *(const float4*)&x[e];
        float4 pv = *(const float4*)&pe[e];
        short4v o;
        o[0] = (short)f2bf(xv.x + pv.x);
        o[1] = (short)f2bf(xv.y + pv.y);
        o[2] = (short)f2bf(xv.z + pv.z);
        o[3] = (short)f2bf(xv.w + pv.w);
        *(short4v*)&qbf[e] = o;
    }
}

// ============ shared MFMA inner block: 128x128 tile, 4 waves 2x2, 4x4 frags ============
__device__ __forceinline__ void mfma_block(const short A[][40], const short B[][40],
                                           int wm, int wn, int lane, float4v acc[4][4]) {
    int m_base = wm + (lane & 15);
    int n_base = wn + (lane & 15);
    int q8 = (lane >> 4) * 8;
    short8 af[4], bf[4];
#pragma unroll
    for (int i = 0; i < 4; ++i) af[i] = *(const short8*)&A[m_base + i * 16][q8];
#pragma unroll
    for (int j = 0; j < 4; ++j) bf[j] = *(const short8*)&B[n_base + j * 16][q8];
#pragma unroll
    for (int i = 0; i < 4; ++i)
#pragma unroll
        for (int j = 0; j < 4; ++j)
            acc[i][j] = __builtin_amdgcn_mfma_f32_16x16x32_bf16(af[i], bf[j], acc[i][j], 0, 0, 0);
}

// ============ fused value GEMM (blocks 0..473) + query GEMM (blocks 474..985) ============
__global__ __launch_bounds__(256) void gemm_vq(const unsigned short* __restrict__ fT,
                                               const unsigned short* __restrict__ wT,
                                               const float* __restrict__ bv,
                                               unsigned short* __restrict__ vws,
                                               const unsigned short* __restrict__ qbf,
                                               const float* __restrict__ boff,
                                               const float* __restrict__ battn,
                                               float* __restrict__ qraw) {
    __shared__ short A[128][40];
    __shared__ short B[128][40];
    const int tid = threadIdx.x;
    const int lane = tid & 63, wave = tid >> 6;
    const int wm = (wave & 1) * 64, wn = (wave >> 1) * 64;
    const int id = blockIdx.x;
    float4v acc[4][4];
#pragma unroll
    for (int i = 0; i < 4; ++i)
#pragma unroll
        for (int j = 0; j < 4; ++j) acc[i][j] = (float4v){0.f, 0.f, 0.f, 0.f};

    if (id < 474) {
        // ---- value path ----
        int pb = id / 6, rem = id % 6;
        int nb = rem >> 1, b = rem & 1;
        int pbl, HW; size_t ftoff, voff;
        if (pb < 60)      { pbl = pb;      HW = 7680; ftoff = FT_L0; voff = VOFF_L0; }
        else if (pb < 75) { pbl = pb - 60; HW = 1920; ftoff = FT_L1; voff = VOFF_L1; }
        else              { pbl = pb - 75; HW = 480;  ftoff = FT_L2; voff = VOFF_L2; }
        const int p0 = pbl * 128, n0 = nb * 128;
        const unsigned short* Asrc = fT + ftoff + (size_t)b * HW * DM_;
        const unsigned short* wvT = wT + WVT_OFF;

        for (int k0 = 0; k0 < DM_; k0 += 32) {
#pragma unroll
            for (int it = 0; it < 2; ++it) {
                int idx = tid + it * 256;
                int r = idx >> 2, sg = idx & 3;
                int p = p0 + r; if (p >= HW) p = HW - 1;
                *(short8*)&A[r][sg * 8] = *(const short8*)&Asrc[(size_t)p * DM_ + k0 + sg * 8];
                *(short8*)&B[r][sg * 8] = *(const short8*)&wvT[(size_t)(n0 + r) * DM_ + k0 + sg * 8];
            }
            __syncthreads();
            mfma_block(A, B, wm, wn, lane, acc);
            __syncthreads();
        }
        int colb = n0 + wn + (lane & 15);
        int rowq = (lane >> 4) * 4;
#pragma unroll
        for (int i = 0; i < 4; ++i)
#pragma unroll
            for (int j = 0; j < 4; ++j) {
                int n = colb + j * 16;
                int h = n >> 6, d = n & 63;
                float bias = bv[n];
#pragma unroll
                for (int r = 0; r < 4; ++r) {
                    int p = p0 + wm + i * 16 + rowq + r;
                    if (p < HW)
                        vws[voff + ((size_t)(b * NH_ + h) * HW + p) * DH_ + d] = f2bf(acc[i][j][r] + bias);
                }
            }
    } else {
        // ---- query path (bf16 staging from qbf) ----
        int qid = id - 474;
        const int m0 = (qid & 127) * 128, n0 = (qid >> 7) * 128;
        for (int k0 = 0; k0 < DM_; k0 += 32) {
#pragma unroll
            for (int it = 0; it < 2; ++it) {
                int idx = tid + it * 256;
                int r = idx >> 2, sg = idx & 3;
                *(short8*)&A[r][sg * 8] = *(const short8*)&qbf[(size_t)(m0 + r) * DM_ + k0 + sg * 8];
                int g = n0 + r;
                short8 bz = (short8)0;
                if (g < 486) bz = *(const short8*)&wT[WOFFT_OFF + (size_t)g * DM_ + k0 + sg * 8];
                *(short8*)&B[r][sg * 8] = bz;
            }
            __syncthreads();
            mfma_block(A, B, wm, wn, lane, acc);
            __syncthreads();
        }
        int colb = n0 + wn + (lane & 15);
        int rowq = (lane >> 4) * 4;
#pragma unroll
        for (int i = 0; i < 4; ++i)
#pragma unroll
            for (int j = 0; j < 4; ++j) {
                int n = colb + j * 16;
                if (n < 486) {
                    float bias = (n < 324) ? boff[n] : battn[n - 324];
#pragma unroll
                    for (int r = 0; r < 4; ++r) {
                        int m = m0 + wm + i * 16 + rowq + r;
                        qraw[(size_t)m * 486 + n] = acc[i][j][r] + bias;
                    }
                }
            }
    }
}

// ============ fused softmax + projection + gather, 2 queries per block ============
// plan LDS (flat): plane = q*4 + corner (corner = (y<<1)|x); entry = plane*177 + h*27 + tap
// gather lanes: q = lane>>5, corner = (lane>>3)&3, chunk = lane&7 (16B of the 128B pixel row)
// one global_load_dwordx4 per tap covers BOTH queries and all 4 corners.
// __launch_bounds__(384,5): VGPR cap ~96 so the 6-deep load batch stays in registers (r7 spilled at cap 80).
__global__ __launch_bounds__(384, 5) void sample_kernel(const float* __restrict__ qraw,
                                                        const float* __restrict__ coor,
                                                        const float* __restrict__ cam2img,
                                                        const float* __restrict__ l2c,
                                                        const unsigned short* __restrict__ vws,
                                                        unsigned short* __restrict__ mid) {
    __shared__ int2 s_plan[1416];   // 8 planes x 177
    const int tid = threadIdx.x;
    const int bq0 = blockIdx.x * 2;

    {
        int q = tid >= 192;
        int t = tid - q * 192;
        int bq = bq0 + q;
        int b = bq >> 13;
        int h = t >> 5, j = t & 31;
        bool act = j < 27;
        float logit = act ? qraw[(size_t)bq * 486 + 324 + h * 27 + j] : -1e30f;
        float m = logit;
#pragma unroll
        for (int msk = 16; msk >= 1; msk >>= 1) m = fmaxf(m, __shfl_xor(m, msk, 32));
        float e = act ? __expf(logit - m) : 0.f;
        float ssum = e;
#pragma unroll
        for (int msk = 16; msk >= 1; msk >>= 1) ssum += __shfl_xor(ssum, msk, 32);
        if (act) {
            float attn = e * __frcp_rn(ssum);
            int l = (j >= 18) ? 2 : ((j >= 9) ? 1 : 0);
            int wl = 160 >> l, hl = 48 >> l;
            int HWl = (l == 0) ? 7680 : ((l == 1) ? 1920 : 480);
            int lvlb = (l == 0) ? 0 : ((l == 1) ? 11796480 : 14745600);
            float sc = (l == 0) ? 0.125f : ((l == 1) ? 0.0625f : 0.03125f);
            float c0 = coor[(size_t)bq * 3 + 0];
            float c1 = coor[(size_t)bq * 3 + 1];
            float c2 = coor[(size_t)bq * 3 + 2];
            const float* L = l2c + b * 16;
            const float* C = cam2img + b * 16;
            float pc0 = L[0] * c0 + L[1] * c1 + L[2]  * c2 + L[3];
            float pc1 = L[4] * c0 + L[5] * c1 + L[6]  * c2 + L[7];
            float pc2 = L[8] * c0 + L[9] * c1 + L[10] * c2 + L[11];
            float q0 = C[0] * pc0 + C[1] * pc1 + C[2]  * pc2 + C[3];
            float q1 = C[4] * pc0 + C[5] * pc1 + C[6]  * pc2 + C[7];
            float q2 = C[8] * pc0 + C[9] * pc1 + C[10] * pc2 + C[11];
            float rz = __frcp_rn(q2);
            float refx = q0 * rz * sc, refy = q1 * rz * sc;
            float2 oxy = *(const float2*)&qraw[(size_t)bq * 486 + h * 54 + j * 2];
            float X = refx + oxy.x - 0.5f;
            float Y = refy + oxy.y - 0.5f;
            float x0f = floorf(X), y0f = floorf(Y);
            float fx = X - x0f, fy = Y - y0f;
            int ix = (int)x0f, iy = (int)y0f;
            int bx = min(max(ix, 0), wl - 2);
            float wx0 = ((bx == ix) ? (1.f - fx) : 0.f) + ((bx == ix + 1) ? fx : 0.f);
            float wx1 = ((bx + 1 == ix) ? (1.f - fx) : 0.f) + ((bx + 1 == ix + 1) ? fx : 0.f);
            int cy0 = min(max(iy, 0), hl - 1);
            int cy1 = min(max(iy + 1, 0), hl - 1);
            float wy0 = (iy >= 0 && iy < hl) ? (1.f - fy) : 0.f;
            float wy1 = (iy + 1 >= 0 && iy + 1 < hl) ? fy : 0.f;
            int jj = h * 27 + j;
            int slice = (b * NH_ + h) * HWl;
            int off0 = lvlb + (slice + cy0 * wl + bx) * 128;
            int off1 = lvlb + (slice + cy1 * wl + bx) * 128;
            int pb = q * 4 * 177 + jj;
            s_plan[pb]           = make_int2(off0,       __float_as_int(attn * wy0 * wx0));
            s_plan[pb + 177]     = make_int2(off0 + 128, __float_as_int(attn * wy0 * wx1));
            s_plan[pb + 2 * 177] = make_int2(off1,       __float_as_int(attn * wy1 * wx0));
            s_plan[pb + 3 * 177] = make_int2(off1 + 128, __float_as_int(attn * wy1 * wx1));
        }
    }
    __syncthreads();

    const int h = tid >> 6;
    const int lane = tid & 63;
    const int plane = lane >> 3;                     // q*4 + corner
    const unsigned cb = (unsigned)((lane & 7) << 4); // 16B chunk within pixel row
    const char* vbase = (const char*)vws;
    const int2* pl = &s_plan[plane * 177 + h * 27];
    float a[8];
#pragma unroll
    for (int i = 0; i < 8; ++i) a[i] = 0.f;

    int g0 = 0;
#pragma unroll
    for (int g = 0; g < 5; ++g) {
        const int N = (g < 4) ? 6 : 3;               // 6+6+6+6+3 = 27
        int2 pw[6];
        uint4 d[6];
#pragma unroll
        for (int t = 0; t < N; ++t) pw[t] = pl[g0 + t];
#pragma unroll
        for (int t = 0; t < N; ++t) d[t] = *(const uint4*)(vbase + ((unsigned)pw[t].x + cb));
#pragma unroll
        for (int t = 0; t < N; ++t) {
            float w = __int_as_float(pw[t].y);
            a[0] = fmaf(w, __uint_as_float(d[t].x << 16), a[0]);
            a[1] = fmaf(w, __uint_as_float(d[t].x & 0xffff0000u), a[1]);
            a[2] = fmaf(w, __uint_as_float(d[t].y << 16), a[2]);
            a[3] = fmaf(w, __uint_as_float(d[t].y & 0xffff0000u), a[3]);
            a[4] = fmaf(w, __uint_as_float(d[t].z << 16), a[4]);
            a[5] = fmaf(w, __uint_as_float(d[t].z & 0xffff0000u), a[5]);
            a[6] = fmaf(w, __uint_as_float(d[t].w << 16), a[6]);
            a[7] = fmaf(w, __uint_as_float(d[t].w & 0xffff0000u), a[7]);
        }
        g0 += N;
    }

    // reduce over corner bits (lane bits 3,4)
#pragma unroll
    for (int i = 0; i < 8; ++i) {
        a[i] += __shfl_xor(a[i], 8, 64);
        a[i] += __shfl_xor(a[i], 16, 64);
    }
    if (((lane >> 3) & 3) == 0) {
        int q = lane >> 5;
        uint4 pk;
        pk.x = (unsigned)f2bf(a[0]) | ((unsigned)f2bf(a[1]) << 16);
        pk.y = (unsigned)f2bf(a[2]) | ((unsigned)f2bf(a[3]) << 16);
        pk.z = (unsigned)f2bf(a[4]) | ((unsigned)f2bf(a[5]) << 16);
        pk.w = (unsigned)f2bf(a[6]) | ((unsigned)f2bf(a[7]) << 16);
        *(uint4*)&mid[(size_t)(bq0 + q) * 384 + h * DH_ + ((lane & 7) << 3)] = pk;
    }
}

// ============ out GEMM: 64x128 tiles (512 blocks, 2/CU) ============
__global__ __launch_bounds__(256) void out_gemm(const unsigned short* __restrict__ mid,
                                                const unsigned short* __restrict__ woT,
                                                const float* __restrict__ bout,
                                                float* __restrict__ out) {
    __shared__ short A[64][40];
    __shared__ short B[128][40];
    const int tid = threadIdx.x;
    const int m0 = blockIdx.x * 64, n0 = blockIdx.y * 128;
    const int lane = tid & 63, wave = tid >> 6;
    const int wn = wave * 32;
    float4v acc[4][2];
#pragma unroll
    for (int i = 0; i < 4; ++i)
#pragma unroll
        for (int j = 0; j < 2; ++j) acc[i][j] = (float4v){0.f, 0.f, 0.f, 0.f};

    for (int k0 = 0; k0 < 384; k0 += 32) {
        {
            int r = tid >> 2, sg = tid & 3;
            *(short8*)&A[r][sg * 8] = *(const short8*)&mid[(size_t)(m0 + r) * 384 + k0 + sg * 8];
        }
#pragma unroll
        for (int it = 0; it < 2; ++it) {
            int idx = tid + it * 256;
            int r = idx >> 2, sg = idx & 3;
            *(short8*)&B[r][sg * 8] = *(const short8*)&woT[(size_t)(n0 + r) * 384 + k0 + sg * 8];
        }
        __syncthreads();
        {
            int m_base = lane & 15;
            int n_base = wn + (lane & 15);
            int q8 = (lane >> 4) * 8;
            short8 af[4], bf[2];
#pragma unroll
            for (int i = 0; i < 4; ++i) af[i] = *(const short8*)&A[m_base + i * 16][q8];
#pragma unroll
            for (int j = 0; j < 2; ++j) bf[j] = *(const short8*)&B[n_base + j * 16][q8];
#pragma unroll
            for (int i = 0; i < 4; ++i)
#pragma unroll
                for (int j = 0; j < 2; ++j)
                    acc[i][j] = __builtin_amdgcn_mfma_f32_16x16x32_bf16(af[i], bf[j], acc[i][j], 0, 0, 0);
        }
        __syncthreads();
    }
    int colb = n0 + wn + (lane & 15);
    int rowq = (lane >> 4) * 4;
#pragma unroll
    for (int i = 0; i < 4; ++i)
#pragma unroll
        for (int j = 0; j < 2; ++j) {
            int n = colb + j * 16;
            float bias = bout[n];
#pragma unroll
            for (int r = 0; r < 4; ++r) {
                int m = m0 + i * 16 + rowq + r;
                out[(size_t)m * 256 + n] = acc[i][j][r] + bias;
            }
        }
}

extern "C" void kernel_launch(void* const* d_in, const int* in_sizes, int n_in,
                              void* d_out, int out_size, void* d_ws, size_t ws_size,
                              hipStream_t stream) {
    const float* x      = (const float*)d_in[0];
    const float* pe     = (const float*)d_in[1];
    const float* coor   = (const float*)d_in[2];
    const float* c2i    = (const float*)d_in[3];
    const float* l2c    = (const float*)d_in[4];
    const float* feat0  = (const float*)d_in[5];
    const float* feat1  = (const float*)d_in[6];
    const float* feat2  = (const float*)d_in[7];
    const float* Wv     = (const float*)d_in[8];
    const float* bv     = (const float*)d_in[9];
    const float* Woff   = (const float*)d_in[10];
    const float* boff   = (const float*)d_in[11];
    const float* Wattn  = (const float*)d_in[12];
    const float* battn  = (const float*)d_in[13];
    const float* Wout   = (const float*)d_in[14];
    const float* bout   = (const float*)d_in[15];

    unsigned short* vws = (unsigned short*)d_ws;
    float* qraw         = (float*)((char*)d_ws + QRAW_BYTE_OFF);
    unsigned short* mid = (unsigned short*)((char*)d_ws + MID_BYTE_OFF);
    unsigned short* qbf = (unsigned short*)((char*)d_ws + QBF_BYTE_OFF);
    unsigned short* wT  = (unsigned short*)((char*)d_ws + WT_BYTE_OFF);
    unsigned short* fT  = (unsigned short*)((char*)d_ws + FEATT_BYTE_OFF);
    float* out          = (float*)d_out;

    prep_all<<<dim3(7190), 256, 0, stream>>>(Wv, Woff, Wattn, Wout, feat0, feat1, feat2,
                                             x, pe, wT, fT, qbf);
    gemm_vq<<<dim3(986), 256, 0, stream>>>(fT, wT, bv, vws, qbf, boff, battn, qraw);
    sample_kernel<<<dim3(BATCH * NQ_ / 2), 384, 0, stream>>>(qraw, coor, c2i, l2c, vws, mid);
    out_gemm<<<dim3(256, 2), 256, 0, stream>>>(mid, wT + WOUTT_OFF, bout, out);
}

// Round 9
// 221.828 us; speedup vs baseline: 1.4152x; 1.0334x over previous
//
#include <hip/hip_runtime.h>
#include <hip/hip_bf16.h>

#define NQ_   8192
#define DM_   256
#define NH_   6
#define DH_   64
#define BATCH 2

typedef __attribute__((ext_vector_type(8))) short short8;
typedef __attribute__((ext_vector_type(4))) short short4v;
typedef __attribute__((ext_vector_type(4))) float float4v;

// ---------------- workspace layout ----------------
static const size_t VOFF_L0 = 0;
static const size_t VOFF_L1 = 5898240;
static const size_t VOFF_L2 = 7372800;
static const size_t QRAW_BYTE_OFF  = 15482880;
static const size_t MID_BYTE_OFF   = 47333376;   // mid bf16 [16384][384]
static const size_t QBF_BYTE_OFF   = 47333376;   // qbf bf16 [16384][256] — aliases mid (lifetimes disjoint)
static const size_t WT_BYTE_OFF    = 59916288;
static const size_t FEATT_BYTE_OFF = 60558336;
// wT element offsets
static const size_t WVT_OFF   = 0;        // 384 rows x 256
static const size_t WOFFT_OFF = 98304;    // 324 rows x 256 (query path may over-read to row 511 — stays inside wT)
static const size_t WOUTT_OFF = 222720;   // 256 rows x 384
// featT element offsets
static const size_t FT_L0 = 0;
static const size_t FT_L1 = 3932160;
static const size_t FT_L2 = 4915200;

__device__ __forceinline__ unsigned short f2bf(float f) {
    unsigned int u = __float_as_uint(f);
    unsigned int r = (u + 0x7fffu + ((u >> 16) & 1u)) >> 16;
    return (unsigned short)r;
}

// async global->LDS, 16B per lane; LDS dest must be wave-uniform base + lane*16
__device__ __forceinline__ void cp16(void* lds, const void* g) {
    __builtin_amdgcn_global_load_lds(
        (const __attribute__((address_space(1))) unsigned int*)g,
        (__attribute__((address_space(3))) unsigned int*)lds, 16, 0, 0);
}

// ============ prep_all: weights T (0..1125) | feat T (1126..6165) | qbf = bf16(x+pe) (6166..7189) ============
__global__ __launch_bounds__(256) void prep_all(const float* __restrict__ Wv,
                                                const float* __restrict__ Woff,
                                                const float* __restrict__ Wattn,
                                                const float* __restrict__ Wout,
                                                const float* __restrict__ feat0,
                                                const float* __restrict__ feat1,
                                                const float* __restrict__ feat2,
                                                const float* __restrict__ x,
                                                const float* __restrict__ pe,
                                                unsigned short* __restrict__ wT,
                                                unsigned short* __restrict__ fT,
                                                unsigned short* __restrict__ qbf) {
    const int pid = blockIdx.x, t = threadIdx.x;
    if (pid < 1126) {
        int r = pid;
        const float* src; int N, n, K; size_t doff;
        if (r < 384)      { src = Wv;    N = 384; n = r;       K = 256; doff = (size_t)r * 256; }
        else if (r < 708) { src = Woff;  N = 324; n = r - 384; K = 256; doff = (size_t)r * 256; }
        else if (r < 870) { src = Wattn; N = 162; n = r - 708; K = 256; doff = (size_t)r * 256; }
        else              { src = Wout;  N = 256; n = r - 870; K = 384; doff = WOUTT_OFF + (size_t)(r - 870) * 384; }
        for (int k = t; k < K; k += 256) wT[doff + k] = f2bf(src[(size_t)k * N + n]);
        return;
    }
    if (pid < 6166) {
        __shared__ float tile[32][33];
        int f = pid - 1126;
        const float* src; unsigned short* dst; int HW;
        if (f < 3840)      { src = feat0; dst = fT + FT_L0; HW = 7680; }
        else if (f < 4800) { src = feat1; dst = fT + FT_L1; HW = 1920; f -= 3840; }
        else               { src = feat2; dst = fT + FT_L2; HW = 480;  f -= 4800; }
        int pb = f >> 4, rem = f & 15, cb = rem >> 1, b = rem & 1;
        int p0 = pb * 32, c0 = cb * 32;
        int tx = t & 31, ty = t >> 5;
#pragma unroll
        for (int i = 0; i < 4; ++i) {
            int c = c0 + ty + i * 8;
            tile[ty + i * 8][tx] = src[((size_t)(b * DM_ + c)) * HW + p0 + tx];
        }
        __syncthreads();
#pragma unroll
        for (int i = 0; i < 4; ++i) {
            int p = p0 + ty + i * 8;
            dst[((size_t)b * HW + p) * DM_ + c0 + tx] = f2bf(tile[tx][ty + i * 8]);
        }
        return;
    }
    // qbf: 1024 blocks, 4096 elements each
    int f = pid - 6166;
#pragma unroll
    for (int i = 0; i < 4; ++i) {
        size_t e = (size_t)f * 4096 + i * 1024 + t * 4;
        float4 xv = *(const float4*)&x[e];
        float4 pv = *(const float4*)&pe[e];
        short4v o;
        o[0] = (short)f2bf(xv.x + pv.x);
        o[1] = (short)f2bf(xv.y + pv.y);
        o[2] = (short)f2bf(xv.z + pv.z);
        o[3] = (short)f2bf(xv.w + pv.w);
        *(short4v*)&qbf[e] = o;
    }
}

// ============ MFMA inner block on unpadded [rows][32] LDS (m97 layout) ============
__device__ __forceinline__ void mfma_block32(const short A[][32], const short B[][32],
                                             int wm, int wn, int lane, float4v acc[4][4]) {
    int m_base = wm + (lane & 15);
    int n_base = wn + (lane & 15);
    int q8 = (lane >> 4) * 8;
    short8 af[4], bf[4];
#pragma unroll
    for (int i = 0; i < 4; ++i) af[i] = *(const short8*)&A[m_base + i * 16][q8];
#pragma unroll
    for (int j = 0; j < 4; ++j) bf[j] = *(const short8*)&B[n_base + j * 16][q8];
#pragma unroll
    for (int i = 0; i < 4; ++i)
#pragma unroll
        for (int j = 0; j < 4; ++j)
            acc[i][j] = __builtin_amdgcn_mfma_f32_16x16x32_bf16(af[i], bf[j], acc[i][j], 0, 0, 0);
}

// ============ fused value GEMM (blocks 0..473) + query GEMM (blocks 474..985) ============
// staging via global_load_lds width-16: LDS dest byte = tid*16 within each 1024B wave chunk
__global__ __launch_bounds__(256) void gemm_vq(const unsigned short* __restrict__ fT,
                                               const unsigned short* __restrict__ wT,
                                               const float* __restrict__ bv,
                                               unsigned short* __restrict__ vws,
                                               const unsigned short* __restrict__ qbf,
                                               const float* __restrict__ boff,
                                               const float* __restrict__ battn,
                                               float* __restrict__ qraw) {
    __shared__ short A[128][32];
    __shared__ short B[128][32];
    const int tid = threadIdx.x;
    const int lane = tid & 63, wave = tid >> 6;
    const int wm = (wave & 1) * 64, wn = (wave >> 1) * 64;
    const int id = blockIdx.x;
    const int r0 = tid >> 2, sg8 = (tid & 3) * 8;
    float4v acc[4][4];
#pragma unroll
    for (int i = 0; i < 4; ++i)
#pragma unroll
        for (int j = 0; j < 4; ++j) acc[i][j] = (float4v){0.f, 0.f, 0.f, 0.f};

    if (id < 474) {
        // ---- value path ----
        int pb = id / 6, rem = id % 6;
        int nb = rem >> 1, b = rem & 1;
        int pbl, HW; size_t ftoff, voff;
        if (pb < 60)      { pbl = pb;      HW = 7680; ftoff = FT_L0; voff = VOFF_L0; }
        else if (pb < 75) { pbl = pb - 60; HW = 1920; ftoff = FT_L1; voff = VOFF_L1; }
        else              { pbl = pb - 75; HW = 480;  ftoff = FT_L2; voff = VOFF_L2; }
        const int p0 = pbl * 128, n0 = nb * 128;
        const unsigned short* Asrc = fT + ftoff + (size_t)b * HW * DM_;
        const unsigned short* wvT = wT + WVT_OFF;
        int p1 = p0 + r0;      if (p1 >= HW) p1 = HW - 1;
        int p2 = p0 + r0 + 64; if (p2 >= HW) p2 = HW - 1;

        for (int k0 = 0; k0 < DM_; k0 += 32) {
            cp16(&A[r0][sg8],      &Asrc[(size_t)p1 * DM_ + k0 + sg8]);
            cp16(&A[r0 + 64][sg8], &Asrc[(size_t)p2 * DM_ + k0 + sg8]);
            cp16(&B[r0][sg8],      &wvT[(size_t)(n0 + r0) * DM_ + k0 + sg8]);
            cp16(&B[r0 + 64][sg8], &wvT[(size_t)(n0 + r0 + 64) * DM_ + k0 + sg8]);
            __syncthreads();
            mfma_block32(A, B, wm, wn, lane, acc);
            __syncthreads();
        }
        int colb = n0 + wn + (lane & 15);
        int rowq = (lane >> 4) * 4;
#pragma unroll
        for (int i = 0; i < 4; ++i)
#pragma unroll
            for (int j = 0; j < 4; ++j) {
                int n = colb + j * 16;
                int h = n >> 6, d = n & 63;
                float bias = bv[n];
#pragma unroll
                for (int r = 0; r < 4; ++r) {
                    int p = p0 + wm + i * 16 + rowq + r;
                    if (p < HW)
                        vws[voff + ((size_t)(b * NH_ + h) * HW + p) * DH_ + d] = f2bf(acc[i][j][r] + bias);
                }
            }
    } else {
        // ---- query path (bf16 staging from qbf) ----
        int qid = id - 474;
        const int m0 = (qid & 127) * 128, n0 = (qid >> 7) * 128;
        const unsigned short* wq = wT + WOFFT_OFF;   // rows up to 511 stay inside wT allocation

        for (int k0 = 0; k0 < DM_; k0 += 32) {
            cp16(&A[r0][sg8],      &qbf[(size_t)(m0 + r0) * DM_ + k0 + sg8]);
            cp16(&A[r0 + 64][sg8], &qbf[(size_t)(m0 + r0 + 64) * DM_ + k0 + sg8]);
            cp16(&B[r0][sg8],      &wq[(size_t)(n0 + r0) * DM_ + k0 + sg8]);
            cp16(&B[r0 + 64][sg8], &wq[(size_t)(n0 + r0 + 64) * DM_ + k0 + sg8]);
            __syncthreads();
            mfma_block32(A, B, wm, wn, lane, acc);
            __syncthreads();
        }
        int colb = n0 + wn + (lane & 15);
        int rowq = (lane >> 4) * 4;
#pragma unroll
        for (int i = 0; i < 4; ++i)
#pragma unroll
            for (int j = 0; j < 4; ++j) {
                int n = colb + j * 16;
                if (n < 486) {
                    float bias = (n < 324) ? boff[n] : battn[n - 324];
#pragma unroll
                    for (int r = 0; r < 4; ++r) {
                        int m = m0 + wm + i * 16 + rowq + r;
                        qraw[(size_t)m * 486 + n] = acc[i][j][r] + bias;
                    }
                }
            }
    }
}

// ============ fused softmax + projection + gather, 2 queries per block (unchanged from R8) ============
__global__ __launch_bounds__(384, 5) void sample_kernel(const float* __restrict__ qraw,
                                                        const float* __restrict__ coor,
                                                        const float* __restrict__ cam2img,
                                                        const float* __restrict__ l2c,
                                                        const unsigned short* __restrict__ vws,
                                                        unsigned short* __restrict__ mid) {
    __shared__ int2 s_plan[1416];   // 8 planes x 177
    const int tid = threadIdx.x;
    const int bq0 = blockIdx.x * 2;

    {
        int q = tid >= 192;
        int t = tid - q * 192;
        int bq = bq0 + q;
        int b = bq >> 13;
        int h = t >> 5, j = t & 31;
        bool act = j < 27;
        float logit = act ? qraw[(size_t)bq * 486 + 324 + h * 27 + j] : -1e30f;
        float m = logit;
#pragma unroll
        for (int msk = 16; msk >= 1; msk >>= 1) m = fmaxf(m, __shfl_xor(m, msk, 32));
        float e = act ? __expf(logit - m) : 0.f;
        float ssum = e;
#pragma unroll
        for (int msk = 16; msk >= 1; msk >>= 1) ssum += __shfl_xor(ssum, msk, 32);
        if (act) {
            float attn = e * __frcp_rn(ssum);
            int l = (j >= 18) ? 2 : ((j >= 9) ? 1 : 0);
            int wl = 160 >> l, hl = 48 >> l;
            int HWl = (l == 0) ? 7680 : ((l == 1) ? 1920 : 480);
            int lvlb = (l == 0) ? 0 : ((l == 1) ? 11796480 : 14745600);
            float sc = (l == 0) ? 0.125f : ((l == 1) ? 0.0625f : 0.03125f);
            float c0 = coor[(size_t)bq * 3 + 0];
            float c1 = coor[(size_t)bq * 3 + 1];
            float c2 = coor[(size_t)bq * 3 + 2];
            const float* L = l2c + b * 16;
            const float* C = cam2img + b * 16;
            float pc0 = L[0] * c0 + L[1] * c1 + L[2]  * c2 + L[3];
            float pc1 = L[4] * c0 + L[5] * c1 + L[6]  * c2 + L[7];
            float pc2 = L[8] * c0 + L[9] * c1 + L[10] * c2 + L[11];
            float q0 = C[0] * pc0 + C[1] * pc1 + C[2]  * pc2 + C[3];
            float q1 = C[4] * pc0 + C[5] * pc1 + C[6]  * pc2 + C[7];
            float q2 = C[8] * pc0 + C[9] * pc1 + C[10] * pc2 + C[11];
            float rz = __frcp_rn(q2);
            float refx = q0 * rz * sc, refy = q1 * rz * sc;
            float2 oxy = *(const float2*)&qraw[(size_t)bq * 486 + h * 54 + j * 2];
            float X = refx + oxy.x - 0.5f;
            float Y = refy + oxy.y - 0.5f;
            float x0f = floorf(X), y0f = floorf(Y);
            float fx = X - x0f, fy = Y - y0f;
            int ix = (int)x0f, iy = (int)y0f;
            int bx = min(max(ix, 0), wl - 2);
            float wx0 = ((bx == ix) ? (1.f - fx) : 0.f) + ((bx == ix + 1) ? fx : 0.f);
            float wx1 = ((bx + 1 == ix) ? (1.f - fx) : 0.f) + ((bx + 1 == ix + 1) ? fx : 0.f);
            int cy0 = min(max(iy, 0), hl - 1);
            int cy1 = min(max(iy + 1, 0), hl - 1);
            float wy0 = (iy >= 0 && iy < hl) ? (1.f - fy) : 0.f;
            float wy1 = (iy + 1 >= 0 && iy + 1 < hl) ? fy : 0.f;
            int jj = h * 27 + j;
            int slice = (b * NH_ + h) * HWl;
            int off0 = lvlb + (slice + cy0 * wl + bx) * 128;
            int off1 = lvlb + (slice + cy1 * wl + bx) * 128;
            int pb = q * 4 * 177 + jj;
            s_plan[pb]           = make_int2(off0,       __float_as_int(attn * wy0 * wx0));
            s_plan[pb + 177]     = make_int2(off0 + 128, __float_as_int(attn * wy0 * wx1));
            s_plan[pb + 2 * 177] = make_int2(off1,       __float_as_int(attn * wy1 * wx0));
            s_plan[pb + 3 * 177] = make_int2(off1 + 128, __float_as_int(attn * wy1 * wx1));
        }
    }
    __syncthreads();

    const int h = tid >> 6;
    const int lane = tid & 63;
    const int plane = lane >> 3;                     // q*4 + corner
    const unsigned cb = (unsigned)((lane & 7) << 4); // 16B chunk within pixel row
    const char* vbase = (const char*)vws;
    const int2* pl = &s_plan[plane * 177 + h * 27];
    float a[8];
#pragma unroll
    for (int i = 0; i < 8; ++i) a[i] = 0.f;

    int g0 = 0;
#pragma unroll
    for (int g = 0; g < 5; ++g) {
        const int N = (g < 4) ? 6 : 3;               // 6+6+6+6+3 = 27
        int2 pw[6];
        uint4 d[6];
#pragma unroll
        for (int t = 0; t < N; ++t) pw[t] = pl[g0 + t];
#pragma unroll
        for (int t = 0; t < N; ++t) d[t] = *(const uint4*)(vbase + ((unsigned)pw[t].x + cb));
#pragma unroll
        for (int t = 0; t < N; ++t) {
            float w = __int_as_float(pw[t].y);
            a[0] = fmaf(w, __uint_as_float(d[t].x << 16), a[0]);
            a[1] = fmaf(w, __uint_as_float(d[t].x & 0xffff0000u), a[1]);
            a[2] = fmaf(w, __uint_as_float(d[t].y << 16), a[2]);
            a[3] = fmaf(w, __uint_as_float(d[t].y & 0xffff0000u), a[3]);
            a[4] = fmaf(w, __uint_as_float(d[t].z << 16), a[4]);
            a[5] = fmaf(w, __uint_as_float(d[t].z & 0xffff0000u), a[5]);
            a[6] = fmaf(w, __uint_as_float(d[t].w << 16), a[6]);
            a[7] = fmaf(w, __uint_as_float(d[t].w & 0xffff0000u), a[7]);
        }
        g0 += N;
    }

#pragma unroll
    for (int i = 0; i < 8; ++i) {
        a[i] += __shfl_xor(a[i], 8, 64);
        a[i] += __shfl_xor(a[i], 16, 64);
    }
    if (((lane >> 3) & 3) == 0) {
        int q = lane >> 5;
        uint4 pk;
        pk.x = (unsigned)f2bf(a[0]) | ((unsigned)f2bf(a[1]) << 16);
        pk.y = (unsigned)f2bf(a[2]) | ((unsigned)f2bf(a[3]) << 16);
        pk.z = (unsigned)f2bf(a[4]) | ((unsigned)f2bf(a[5]) << 16);
        pk.w = (unsigned)f2bf(a[6]) | ((unsigned)f2bf(a[7]) << 16);
        *(uint4*)&mid[(size_t)(bq0 + q) * 384 + h * DH_ + ((lane & 7) << 3)] = pk;
    }
}

// ============ out GEMM: 64x128 tiles, async staging ============
__global__ __launch_bounds__(256) void out_gemm(const unsigned short* __restrict__ mid,
                                                const unsigned short* __restrict__ woT,
                                                const float* __restrict__ bout,
                                                float* __restrict__ out) {
    __shared__ short A[64][32];
    __shared__ short B[128][32];
    const int tid = threadIdx.x;
    const int m0 = blockIdx.x * 64, n0 = blockIdx.y * 128;
    const int lane = tid & 63, wave = tid >> 6;
    const int wn = wave * 32;
    const int r0 = tid >> 2, sg8 = (tid & 3) * 8;
    float4v acc[4][2];
#pragma unroll
    for (int i = 0; i < 4; ++i)
#pragma unroll
        for (int j = 0; j < 2; ++j) acc[i][j] = (float4v){0.f, 0.f, 0.f, 0.f};

    for (int k0 = 0; k0 < 384; k0 += 32) {
        cp16(&A[r0][sg8],      &mid[(size_t)(m0 + r0) * 384 + k0 + sg8]);
        cp16(&B[r0][sg8],      &woT[(size_t)(n0 + r0) * 384 + k0 + sg8]);
        cp16(&B[r0 + 64][sg8], &woT[(size_t)(n0 + r0 + 64) * 384 + k0 + sg8]);
        __syncthreads();
        {
            int m_base = lane & 15;
            int n_base = wn + (lane & 15);
            int q8 = (lane >> 4) * 8;
            short8 af[4], bf[2];
#pragma unroll
            for (int i = 0; i < 4; ++i) af[i] = *(const short8*)&A[m_base + i * 16][q8];
#pragma unroll
            for (int j = 0; j < 2; ++j) bf[j] = *(const short8*)&B[n_base + j * 16][q8];
#pragma unroll
            for (int i = 0; i < 4; ++i)
#pragma unroll
                for (int j = 0; j < 2; ++j)
                    acc[i][j] = __builtin_amdgcn_mfma_f32_16x16x32_bf16(af[i], bf[j], acc[i][j], 0, 0, 0);
        }
        __syncthreads();
    }
    int colb = n0 + wn + (lane & 15);
    int rowq = (lane >> 4) * 4;
#pragma unroll
    for (int i = 0; i < 4; ++i)
#pragma unroll
        for (int j = 0; j < 2; ++j) {
            int n = colb + j * 16;
            float bias = bout[n];
#pragma unroll
            for (int r = 0; r < 4; ++r) {
                int m = m0 + i * 16 + rowq + r;
                out[(size_t)m * 256 + n] = acc[i][j][r] + bias;
            }
        }
}

extern "C" void kernel_launch(void* const* d_in, const int* in_sizes, int n_in,
                              void* d_out, int out_size, void* d_ws, size_t ws_size,
                              hipStream_t stream) {
    const float* x      = (const float*)d_in[0];
    const float* pe     = (const float*)d_in[1];
    const float* coor   = (const float*)d_in[2];
    const float* c2i    = (const float*)d_in[3];
    const float* l2c    = (const float*)d_in[4];
    const float* feat0  = (const float*)d_in[5];
    const float* feat1  = (const float*)d_in[6];
    const float* feat2  = (const float*)d_in[7];
    const float* Wv     = (const float*)d_in[8];
    const float* bv     = (const float*)d_in[9];
    const float* Woff   = (const float*)d_in[10];
    const float* boff   = (const float*)d_in[11];
    const float* Wattn  = (const float*)d_in[12];
    const float* battn  = (const float*)d_in[13];
    const float* Wout   = (const float*)d_in[14];
    const float* bout   = (const float*)d_in[15];

    unsigned short* vws = (unsigned short*)d_ws;
    float* qraw         = (float*)((char*)d_ws + QRAW_BYTE_OFF);
    unsigned short* mid = (unsigned short*)((char*)d_ws + MID_BYTE_OFF);
    unsigned short* qbf = (unsigned short*)((char*)d_ws + QBF_BYTE_OFF);
    unsigned short* wT  = (unsigned short*)((char*)d_ws + WT_BYTE_OFF);
    unsigned short* fT  = (unsigned short*)((char*)d_ws + FEATT_BYTE_OFF);
    float* out          = (float*)d_out;

    prep_all<<<dim3(7190), 256, 0, stream>>>(Wv, Woff, Wattn, Wout, feat0, feat1, feat2,
                                             x, pe, wT, fT, qbf);
    gemm_vq<<<dim3(986), 256, 0, stream>>>(fT, wT, bv, vws, qbf, boff, battn, qraw);
    sample_kernel<<<dim3(BATCH * NQ_ / 2), 384, 0, stream>>>(qraw, coor, c2i, l2c, vws, mid);
    out_gemm<<<dim3(256, 2), 256, 0, stream>>>(mid, wT + WOUTT_OFF, bout, out);
}

// Round 10
// 215.973 us; speedup vs baseline: 1.4536x; 1.0271x over previous
//
#include <hip/hip_runtime.h>
#include <hip/hip_bf16.h>

#define NQ_   8192
#define DM_   256
#define NH_   6
#define DH_   64
#define BATCH 2

typedef __attribute__((ext_vector_type(8))) short short8;
typedef __attribute__((ext_vector_type(4))) short short4v;
typedef __attribute__((ext_vector_type(4))) float float4v;
typedef __attribute__((ext_vector_type(2))) float f32x2;

// ---------------- workspace layout ----------------
static const size_t VOFF_L0 = 0;
static const size_t VOFF_L1 = 5898240;
static const size_t VOFF_L2 = 7372800;
static const size_t QRAW_BYTE_OFF  = 15482880;
static const size_t MID_BYTE_OFF   = 47333376;   // mid bf16 [16384][384]
static const size_t QBF_BYTE_OFF   = 47333376;   // qbf bf16 [16384][256] — aliases mid (lifetimes disjoint)
static const size_t WT_BYTE_OFF    = 59916288;
static const size_t FEATT_BYTE_OFF = 60558336;
// wT element offsets
static const size_t WVT_OFF   = 0;        // 384 rows x 256
static const size_t WOFFT_OFF = 98304;    // 324 rows x 256 (query path may over-read to row 511 — stays inside wT)
static const size_t WOUTT_OFF = 222720;   // 256 rows x 384
// featT element offsets
static const size_t FT_L0 = 0;
static const size_t FT_L1 = 3932160;
static const size_t FT_L2 = 4915200;

__device__ __forceinline__ unsigned short f2bf(float f) {
    unsigned int u = __float_as_uint(f);
    unsigned int r = (u + 0x7fffu + ((u >> 16) & 1u)) >> 16;
    return (unsigned short)r;
}

// async global->LDS, 16B per lane; LDS dest must be wave-uniform base + lane*16
__device__ __forceinline__ void cp16(void* lds, const void* g) {
    __builtin_amdgcn_global_load_lds(
        (const __attribute__((address_space(1))) unsigned int*)g,
        (__attribute__((address_space(3))) unsigned int*)lds, 16, 0, 0);
}

// ============ prep_all: weights T (0..1125) | feat T (1126..3645, 64c x 32p tiles) | qbf (3646..4669) ============
__global__ __launch_bounds__(256) void prep_all(const float* __restrict__ Wv,
                                                const float* __restrict__ Woff,
                                                const float* __restrict__ Wattn,
                                                const float* __restrict__ Wout,
                                                const float* __restrict__ feat0,
                                                const float* __restrict__ feat1,
                                                const float* __restrict__ feat2,
                                                const float* __restrict__ x,
                                                const float* __restrict__ pe,
                                                unsigned short* __restrict__ wT,
                                                unsigned short* __restrict__ fT,
                                                unsigned short* __restrict__ qbf) {
    const int pid = blockIdx.x, t = threadIdx.x;
    if (pid < 1126) {
        int r = pid;
        const float* src; int N, n, K; size_t doff;
        if (r < 384)      { src = Wv;    N = 384; n = r;       K = 256; doff = (size_t)r * 256; }
        else if (r < 708) { src = Woff;  N = 324; n = r - 384; K = 256; doff = (size_t)r * 256; }
        else if (r < 870) { src = Wattn; N = 162; n = r - 708; K = 256; doff = (size_t)r * 256; }
        else              { src = Wout;  N = 256; n = r - 870; K = 384; doff = WOUTT_OFF + (size_t)(r - 870) * 384; }
        for (int k = t; k < K; k += 256) wT[doff + k] = f2bf(src[(size_t)k * N + n]);
        return;
    }
    if (pid < 3646) {
        // feat transpose: 64c x 32p tile; reads 128B-coalesced, writes 128B-coalesced
        __shared__ float tile[64][33];
        int f = pid - 1126;
        const float* src; unsigned short* dst; int HW;
        if (f < 1920)      { src = feat0; dst = fT + FT_L0; HW = 7680; }
        else if (f < 2400) { src = feat1; dst = fT + FT_L1; HW = 1920; f -= 1920; }
        else               { src = feat2; dst = fT + FT_L2; HW = 480;  f -= 2400; }
        int pb = f >> 3, rem = f & 7, cb = rem >> 1, b = rem & 1;
        int p0 = pb * 32, c0 = cb * 64;
        {
            int px = t & 31, cy = t >> 5;          // cy 0..7
#pragma unroll
            for (int i = 0; i < 8; ++i) {
                int cr = cy + i * 8;
                tile[cr][px] = src[((size_t)(b * DM_ + c0 + cr)) * HW + p0 + px];
            }
        }
        __syncthreads();
        {
            int cx = t & 63, py = t >> 6;          // py 0..3
#pragma unroll
            for (int i = 0; i < 8; ++i) {
                int pr = py + i * 4;
                dst[((size_t)b * HW + p0 + pr) * DM_ + c0 + cx] = f2bf(tile[cx][pr]);
            }
        }
        return;
    }
    // qbf: 1024 blocks, 4096 elements each
    int f = pid - 3646;
#pragma unroll
    for (int i = 0; i < 4; ++i) {
        size_t e = (size_t)f * 4096 + i * 1024 + t * 4;
        float4 xv = *(const float4*)&x[e];
        float4 pv = *(const float4*)&pe[e];
        short4v o;
        o[0] = (short)f2bf(xv.x + pv.x);
        o[1] = (short)f2bf(xv.y + pv.y);
        o[2] = (short)f2bf(xv.z + pv.z);
        o[3] = (short)f2bf(xv.w + pv.w);
        *(short4v*)&qbf[e] = o;
    }
}

// ============ MFMA inner block on unpadded [rows][32] LDS (m97 layout) ============
__device__ __forceinline__ void mfma_block32(const short A[][32], const short B[][32],
                                             int wm, int wn, int lane, float4v acc[4][4]) {
    int m_base = wm + (lane & 15);
    int n_base = wn + (lane & 15);
    int q8 = (lane >> 4) * 8;
    short8 af[4], bf[4];
#pragma unroll
    for (int i = 0; i < 4; ++i) af[i] = *(const short8*)&A[m_base + i * 16][q8];
#pragma unroll
    for (int j = 0; j < 4; ++j) bf[j] = *(const short8*)&B[n_base + j * 16][q8];
#pragma unroll
    for (int i = 0; i < 4; ++i)
#pragma unroll
        for (int j = 0; j < 4; ++j)
            acc[i][j] = __builtin_amdgcn_mfma_f32_16x16x32_bf16(af[i], bf[j], acc[i][j], 0, 0, 0);
}

// ============ fused value GEMM (blocks 0..473) + query GEMM (blocks 474..985) ============
__global__ __launch_bounds__(256) void gemm_vq(const unsigned short* __restrict__ fT,
                                               const unsigned short* __restrict__ wT,
                                               const float* __restrict__ bv,
                                               unsigned short* __restrict__ vws,
                                               const unsigned short* __restrict__ qbf,
                                               const float* __restrict__ boff,
                                               const float* __restrict__ battn,
                                               float* __restrict__ qraw) {
    __shared__ short A[128][32];
    __shared__ short B[128][32];
    const int tid = threadIdx.x;
    const int lane = tid & 63, wave = tid >> 6;
    const int wm = (wave & 1) * 64, wn = (wave >> 1) * 64;
    const int id = blockIdx.x;
    const int r0 = tid >> 2, sg8 = (tid & 3) * 8;
    float4v acc[4][4];
#pragma unroll
    for (int i = 0; i < 4; ++i)
#pragma unroll
        for (int j = 0; j < 4; ++j) acc[i][j] = (float4v){0.f, 0.f, 0.f, 0.f};

    if (id < 474) {
        // ---- value path ----
        int pb = id / 6, rem = id % 6;
        int nb = rem >> 1, b = rem & 1;
        int pbl, HW; size_t ftoff, voff;
        if (pb < 60)      { pbl = pb;      HW = 7680; ftoff = FT_L0; voff = VOFF_L0; }
        else if (pb < 75) { pbl = pb - 60; HW = 1920; ftoff = FT_L1; voff = VOFF_L1; }
        else              { pbl = pb - 75; HW = 480;  ftoff = FT_L2; voff = VOFF_L2; }
        const int p0 = pbl * 128, n0 = nb * 128;
        const unsigned short* Asrc = fT + ftoff + (size_t)b * HW * DM_;
        const unsigned short* wvT = wT + WVT_OFF;
        int p1 = p0 + r0;      if (p1 >= HW) p1 = HW - 1;
        int p2 = p0 + r0 + 64; if (p2 >= HW) p2 = HW - 1;

        for (int k0 = 0; k0 < DM_; k0 += 32) {
            cp16(&A[r0][sg8],      &Asrc[(size_t)p1 * DM_ + k0 + sg8]);
            cp16(&A[r0 + 64][sg8], &Asrc[(size_t)p2 * DM_ + k0 + sg8]);
            cp16(&B[r0][sg8],      &wvT[(size_t)(n0 + r0) * DM_ + k0 + sg8]);
            cp16(&B[r0 + 64][sg8], &wvT[(size_t)(n0 + r0 + 64) * DM_ + k0 + sg8]);
            __syncthreads();
            mfma_block32(A, B, wm, wn, lane, acc);
            __syncthreads();
        }
        int colb = n0 + wn + (lane & 15);
        int rowq = (lane >> 4) * 4;
#pragma unroll
        for (int i = 0; i < 4; ++i)
#pragma unroll
            for (int j = 0; j < 4; ++j) {
                int n = colb + j * 16;
                int h = n >> 6, d = n & 63;
                float bias = bv[n];
#pragma unroll
                for (int r = 0; r < 4; ++r) {
                    int p = p0 + wm + i * 16 + rowq + r;
                    if (p < HW)
                        vws[voff + ((size_t)(b * NH_ + h) * HW + p) * DH_ + d] = f2bf(acc[i][j][r] + bias);
                }
            }
    } else {
        // ---- query path (bf16 staging from qbf) ----
        int qid = id - 474;
        const int m0 = (qid & 127) * 128, n0 = (qid >> 7) * 128;
        const unsigned short* wq = wT + WOFFT_OFF;   // rows up to 511 stay inside wT allocation

        for (int k0 = 0; k0 < DM_; k0 += 32) {
            cp16(&A[r0][sg8],      &qbf[(size_t)(m0 + r0) * DM_ + k0 + sg8]);
            cp16(&A[r0 + 64][sg8], &qbf[(size_t)(m0 + r0 + 64) * DM_ + k0 + sg8]);
            cp16(&B[r0][sg8],      &wq[(size_t)(n0 + r0) * DM_ + k0 + sg8]);
            cp16(&B[r0 + 64][sg8], &wq[(size_t)(n0 + r0 + 64) * DM_ + k0 + sg8]);
            __syncthreads();
            mfma_block32(A, B, wm, wn, lane, acc);
            __syncthreads();
        }
        int colb = n0 + wn + (lane & 15);
        int rowq = (lane >> 4) * 4;
#pragma unroll
        for (int i = 0; i < 4; ++i)
#pragma unroll
            for (int j = 0; j < 4; ++j) {
                int n = colb + j * 16;
                if (n < 486) {
                    float bias = (n < 324) ? boff[n] : battn[n - 324];
#pragma unroll
                    for (int r = 0; r < 4; ++r) {
                        int m = m0 + wm + i * 16 + rowq + r;
                        qraw[(size_t)m * 486 + n] = acc[i][j][r] + bias;
                    }
                }
            }
    }
}

// ============ fused softmax + projection + gather, 2 queries per block ============
// gather lanes: q = lane>>5, corner = (lane>>3)&3, chunk = lane&7 (16B of the 128B pixel row)
// packed-f32 accumulation: 4 x v_pk_fma_f32 per tap instead of 8 x v_fma_f32
__global__ __launch_bounds__(384, 5) void sample_kernel(const float* __restrict__ qraw,
                                                        const float* __restrict__ coor,
                                                        const float* __restrict__ cam2img,
                                                        const float* __restrict__ l2c,
                                                        const unsigned short* __restrict__ vws,
                                                        unsigned short* __restrict__ mid) {
    __shared__ int2 s_plan[1416];   // 8 planes x 177
    const int tid = threadIdx.x;
    const int bq0 = blockIdx.x * 2;

    {
        int q = tid >= 192;
        int t = tid - q * 192;
        int bq = bq0 + q;
        int b = bq >> 13;
        int h = t >> 5, j = t & 31;
        bool act = j < 27;
        float logit = act ? qraw[(size_t)bq * 486 + 324 + h * 27 + j] : -1e30f;
        float m = logit;
#pragma unroll
        for (int msk = 16; msk >= 1; msk >>= 1) m = fmaxf(m, __shfl_xor(m, msk, 32));
        float e = act ? __expf(logit - m) : 0.f;
        float ssum = e;
#pragma unroll
        for (int msk = 16; msk >= 1; msk >>= 1) ssum += __shfl_xor(ssum, msk, 32);
        if (act) {
            float attn = e * __frcp_rn(ssum);
            int l = (j >= 18) ? 2 : ((j >= 9) ? 1 : 0);
            int wl = 160 >> l, hl = 48 >> l;
            int HWl = (l == 0) ? 7680 : ((l == 1) ? 1920 : 480);
            int lvlb = (l == 0) ? 0 : ((l == 1) ? 11796480 : 14745600);
            float sc = (l == 0) ? 0.125f : ((l == 1) ? 0.0625f : 0.03125f);
            float c0 = coor[(size_t)bq * 3 + 0];
            float c1 = coor[(size_t)bq * 3 + 1];
            float c2 = coor[(size_t)bq * 3 + 2];
            const float* L = l2c + b * 16;
            const float* C = cam2img + b * 16;
            float pc0 = L[0] * c0 + L[1] * c1 + L[2]  * c2 + L[3];
            float pc1 = L[4] * c0 + L[5] * c1 + L[6]  * c2 + L[7];
            float pc2 = L[8] * c0 + L[9] * c1 + L[10] * c2 + L[11];
            float q0 = C[0] * pc0 + C[1] * pc1 + C[2]  * pc2 + C[3];
            float q1 = C[4] * pc0 + C[5] * pc1 + C[6]  * pc2 + C[7];
            float q2 = C[8] * pc0 + C[9] * pc1 + C[10] * pc2 + C[11];
            float rz = __frcp_rn(q2);
            float refx = q0 * rz * sc, refy = q1 * rz * sc;
            float2 oxy = *(const float2*)&qraw[(size_t)bq * 486 + h * 54 + j * 2];
            float X = refx + oxy.x - 0.5f;
            float Y = refy + oxy.y - 0.5f;
            float x0f = floorf(X), y0f = floorf(Y);
            float fx = X - x0f, fy = Y - y0f;
            int ix = (int)x0f, iy = (int)y0f;
            int bx = min(max(ix, 0), wl - 2);
            float wx0 = ((bx == ix) ? (1.f - fx) : 0.f) + ((bx == ix + 1) ? fx : 0.f);
            float wx1 = ((bx + 1 == ix) ? (1.f - fx) : 0.f) + ((bx + 1 == ix + 1) ? fx : 0.f);
            int cy0 = min(max(iy, 0), hl - 1);
            int cy1 = min(max(iy + 1, 0), hl - 1);
            float wy0 = (iy >= 0 && iy < hl) ? (1.f - fy) : 0.f;
            float wy1 = (iy + 1 >= 0 && iy + 1 < hl) ? fy : 0.f;
            int jj = h * 27 + j;
            int slice = (b * NH_ + h) * HWl;
            int off0 = lvlb + (slice + cy0 * wl + bx) * 128;
            int off1 = lvlb + (slice + cy1 * wl + bx) * 128;
            int pb = q * 4 * 177 + jj;
            s_plan[pb]           = make_int2(off0,       __float_as_int(attn * wy0 * wx0));
            s_plan[pb + 177]     = make_int2(off0 + 128, __float_as_int(attn * wy0 * wx1));
            s_plan[pb + 2 * 177] = make_int2(off1,       __float_as_int(attn * wy1 * wx0));
            s_plan[pb + 3 * 177] = make_int2(off1 + 128, __float_as_int(attn * wy1 * wx1));
        }
    }
    __syncthreads();

    const int h = tid >> 6;
    const int lane = tid & 63;
    const int plane = lane >> 3;                     // q*4 + corner
    const unsigned cb = (unsigned)((lane & 7) << 4); // 16B chunk within pixel row
    const char* vbase = (const char*)vws;
    const int2* pl = &s_plan[plane * 177 + h * 27];
    f32x2 A0 = {0.f, 0.f}, A1 = {0.f, 0.f}, A2 = {0.f, 0.f}, A3 = {0.f, 0.f};

    int g0 = 0;
#pragma unroll
    for (int g = 0; g < 5; ++g) {
        const int N = (g < 4) ? 6 : 3;               // 6+6+6+6+3 = 27
        int2 pw[6];
        uint4 d[6];
#pragma unroll
        for (int t = 0; t < N; ++t) pw[t] = pl[g0 + t];
#pragma unroll
        for (int t = 0; t < N; ++t) d[t] = *(const uint4*)(vbase + ((unsigned)pw[t].x + cb));
#pragma unroll
        for (int t = 0; t < N; ++t) {
            float w = __int_as_float(pw[t].y);
            f32x2 w2 = {w, w};
            f32x2 v0 = {__uint_as_float(d[t].x << 16), __uint_as_float(d[t].x & 0xffff0000u)};
            f32x2 v1 = {__uint_as_float(d[t].y << 16), __uint_as_float(d[t].y & 0xffff0000u)};
            f32x2 v2 = {__uint_as_float(d[t].z << 16), __uint_as_float(d[t].z & 0xffff0000u)};
            f32x2 v3 = {__uint_as_float(d[t].w << 16), __uint_as_float(d[t].w & 0xffff0000u)};
            A0 = __builtin_elementwise_fma(w2, v0, A0);
            A1 = __builtin_elementwise_fma(w2, v1, A1);
            A2 = __builtin_elementwise_fma(w2, v2, A2);
            A3 = __builtin_elementwise_fma(w2, v3, A3);
        }
        g0 += N;
    }

    float a[8] = {A0.x, A0.y, A1.x, A1.y, A2.x, A2.y, A3.x, A3.y};
#pragma unroll
    for (int i = 0; i < 8; ++i) {
        a[i] += __shfl_xor(a[i], 8, 64);
        a[i] += __shfl_xor(a[i], 16, 64);
    }
    if (((lane >> 3) & 3) == 0) {
        int q = lane >> 5;
        uint4 pk;
        pk.x = (unsigned)f2bf(a[0]) | ((unsigned)f2bf(a[1]) << 16);
        pk.y = (unsigned)f2bf(a[2]) | ((unsigned)f2bf(a[3]) << 16);
        pk.z = (unsigned)f2bf(a[4]) | ((unsigned)f2bf(a[5]) << 16);
        pk.w = (unsigned)f2bf(a[6]) | ((unsigned)f2bf(a[7]) << 16);
        *(uint4*)&mid[(size_t)(bq0 + q) * 384 + h * DH_ + ((lane & 7) << 3)] = pk;
    }
}

// ============ out GEMM: 64x128 tiles, async staging ============
__global__ __launch_bounds__(256) void out_gemm(const unsigned short* __restrict__ mid,
                                                const unsigned short* __restrict__ woT,
                                                const float* __restrict__ bout,
                                                float* __restrict__ out) {
    __shared__ short A[64][32];
    __shared__ short B[128][32];
    const int tid = threadIdx.x;
    const int m0 = blockIdx.x * 64, n0 = blockIdx.y * 128;
    const int lane = tid & 63, wave = tid >> 6;
    const int wn = wave * 32;
    const int r0 = tid >> 2, sg8 = (tid & 3) * 8;
    float4v acc[4][2];
#pragma unroll
    for (int i = 0; i < 4; ++i)
#pragma unroll
        for (int j = 0; j < 2; ++j) acc[i][j] = (float4v){0.f, 0.f, 0.f, 0.f};

    for (int k0 = 0; k0 < 384; k0 += 32) {
        cp16(&A[r0][sg8],      &mid[(size_t)(m0 + r0) * 384 + k0 + sg8]);
        cp16(&B[r0][sg8],      &woT[(size_t)(n0 + r0) * 384 + k0 + sg8]);
        cp16(&B[r0 + 64][sg8], &woT[(size_t)(n0 + r0 + 64) * 384 + k0 + sg8]);
        __syncthreads();
        {
            int m_base = lane & 15;
            int n_base = wn + (lane & 15);
            int q8 = (lane >> 4) * 8;
            short8 af[4], bf[2];
#pragma unroll
            for (int i = 0; i < 4; ++i) af[i] = *(const short8*)&A[m_base + i * 16][q8];
#pragma unroll
            for (int j = 0; j < 2; ++j) bf[j] = *(const short8*)&B[n_base + j * 16][q8];
#pragma unroll
            for (int i = 0; i < 4; ++i)
#pragma unroll
                for (int j = 0; j < 2; ++j)
                    acc[i][j] = __builtin_amdgcn_mfma_f32_16x16x32_bf16(af[i], bf[j], acc[i][j], 0, 0, 0);
        }
        __syncthreads();
    }
    int colb = n0 + wn + (lane & 15);
    int rowq = (lane >> 4) * 4;
#pragma unroll
    for (int i = 0; i < 4; ++i)
#pragma unroll
        for (int j = 0; j < 2; ++j) {
            int n = colb + j * 16;
            float bias = bout[n];
#pragma unroll
            for (int r = 0; r < 4; ++r) {
                int m = m0 + i * 16 + rowq + r;
                out[(size_t)m * 256 + n] = acc[i][j][r] + bias;
            }
        }
}

extern "C" void kernel_launch(void* const* d_in, const int* in_sizes, int n_in,
                              void* d_out, int out_size, void* d_ws, size_t ws_size,
                              hipStream_t stream) {
    const float* x      = (const float*)d_in[0];
    const float* pe     = (const float*)d_in[1];
    const float* coor   = (const float*)d_in[2];
    const float* c2i    = (const float*)d_in[3];
    const float* l2c    = (const float*)d_in[4];
    const float* feat0  = (const float*)d_in[5];
    const float* feat1  = (const float*)d_in[6];
    const float* feat2  = (const float*)d_in[7];
    const float* Wv     = (const float*)d_in[8];
    const float* bv     = (const float*)d_in[9];
    const float* Woff   = (const float*)d_in[10];
    const float* boff   = (const float*)d_in[11];
    const float* Wattn  = (const float*)d_in[12];
    const float* battn  = (const float*)d_in[13];
    const float* Wout   = (const float*)d_in[14];
    const float* bout   = (const float*)d_in[15];

    unsigned short* vws = (unsigned short*)d_ws;
    float* qraw         = (float*)((char*)d_ws + QRAW_BYTE_OFF);
    unsigned short* mid = (unsigned short*)((char*)d_ws + MID_BYTE_OFF);
    unsigned short* qbf = (unsigned short*)((char*)d_ws + QBF_BYTE_OFF);
    unsigned short* wT  = (unsigned short*)((char*)d_ws + WT_BYTE_OFF);
    unsigned short* fT  = (unsigned short*)((char*)d_ws + FEATT_BYTE_OFF);
    float* out          = (float*)d_out;

    prep_all<<<dim3(4670), 256, 0, stream>>>(Wv, Woff, Wattn, Wout, feat0, feat1, feat2,
                                             x, pe, wT, fT, qbf);
    gemm_vq<<<dim3(986), 256, 0, stream>>>(fT, wT, bv, vws, qbf, boff, battn, qraw);
    sample_kernel<<<dim3(BATCH * NQ_ / 2), 384, 0, stream>>>(qraw, coor, c2i, l2c, vws, mid);
    out_gemm<<<dim3(256, 2), 256, 0, stream>>>(mid, wT + WOUTT_OFF, bout, out);
}